// Round 3
// baseline (1153.959 us; speedup 1.0000x reference)
//
#include <hip/hip_runtime.h>
#include <math.h>

#define DD 256
#define DHALF 128.0f
#define TILE 16   // 16x16 pixel tile per 256-thread block

__global__ __launch_bounds__(256) void slice_extract_phase_kernel(
    const float* __restrict__ vol,   // (B, 2, D, D, D) float32
    const float* __restrict__ rot,   // (B, 3, 3) float32
    const float* __restrict__ trans, // (B, 2) float32
    float* __restrict__ out)         // (B, 2, D, D) float32
{
    // blockIdx.x = tile*8 + b  (batch fastest -> each batch pinned to one XCD
    // by the round-robin workgroup->XCD dispatch; perf heuristic only)
    const int b    = blockIdx.x & 7;
    const int tile = blockIdx.x >> 3;          // 0..255
    const int ti   = tile >> 4;                // tile row (i block)
    const int tj   = tile & 15;                // tile col (j block)
    const int i = ti * TILE + (threadIdx.x >> 4);
    const int j = tj * TILE + (threadIdx.x & 15);

    // Rotation columns 0,1 (base z == 0). Uniform -> scalar loads.
    const float r00 = rot[b * 9 + 0];
    const float r01 = rot[b * 9 + 1];
    const float r10 = rot[b * 9 + 3];
    const float r11 = rot[b * 9 + 4];
    const float r20 = rot[b * 9 + 6];
    const float r21 = rot[b * 9 + 7];

    // Output index i ~ reference gx (w axis), j ~ gy (h axis): transpose(0,1,3,2).
    const float px = (float)i - DHALF;
    const float py = (float)j - DHALF;

    float x = fmaf(r00, px, fmaf(r01, py, DHALF));
    float y = fmaf(r10, px, fmaf(r11, py, DHALF));
    float z = fmaf(r20, px, fmaf(r21, py, DHALF));

    x = fminf(fmaxf(x, 0.0f), 255.0f);
    y = fminf(fmaxf(y, 0.0f), 255.0f);
    z = fminf(fmaxf(z, 0.0f), 255.0f);

    const float x0f = floorf(x), y0f = floorf(y), z0f = floorf(z);
    const float fx = x - x0f, fy = y - y0f, fz = z - z0f;
    const int x0 = (int)x0f, y0 = (int)y0f, z0 = (int)z0f;
    const int x1 = min(x0 + 1, DD - 1);
    const int y1 = min(y0 + 1, DD - 1);
    const int z1 = min(z0 + 1, DD - 1);

    const size_t plane = (size_t)DD * DD;        // 65536
    const size_t cstride = plane * DD;           // 256^3
    const float* v0 = vol + (size_t)b * 2 * cstride;
    const float* v1 = v0 + cstride;

    const size_t z0o = (size_t)z0 * plane, z1o = (size_t)z1 * plane;
    const size_t y0o = (size_t)y0 * DD,    y1o = (size_t)y1 * DD;
    const size_t o00 = z0o + y0o;
    const size_t o01 = z0o + y1o;
    const size_t o10 = z1o + y0o;
    const size_t o11 = z1o + y1o;

    // Issue all 16 gathers up front (independent; compiler batches them).
    const float a000 = v0[o00 + x0], a001 = v0[o00 + x1];
    const float a010 = v0[o01 + x0], a011 = v0[o01 + x1];
    const float a100 = v0[o10 + x0], a101 = v0[o10 + x1];
    const float a110 = v0[o11 + x0], a111 = v0[o11 + x1];
    const float b000 = v1[o00 + x0], b001 = v1[o00 + x1];
    const float b010 = v1[o01 + x0], b011 = v1[o01 + x1];
    const float b100 = v1[o10 + x0], b101 = v1[o10 + x1];
    const float b110 = v1[o11 + x0], b111 = v1[o11 + x1];

    const float gx0 = 1.0f - fx, gy0 = 1.0f - fy, gz0 = 1.0f - fz;
    const float w000 = gz0 * gy0 * gx0;
    const float w001 = gz0 * gy0 * fx;
    const float w010 = gz0 * fy * gx0;
    const float w011 = gz0 * fy * fx;
    const float w100 = fz * gy0 * gx0;
    const float w101 = fz * gy0 * fx;
    const float w110 = fz * fy * gx0;
    const float w111 = fz * fy * fx;

    float re = a000 * w000 + a001 * w001 + a010 * w010 + a011 * w011 +
               a100 * w100 + a101 * w101 + a110 * w110 + a111 * w111;
    float im = b000 * w000 + b001 * w001 + b010 * w010 + b011 * w011 +
               b100 * w100 + b101 * w101 + b110 * w110 + b111 * w111;

    re *= 16.0f;   // sqrt(256)
    im *= 16.0f;

    // Phase: ang = -(2*pi/256) * S, S = t0*ki + t1*kj. Period in S is exactly
    // 256, so reduce rev = S/256 (exact pow2 scale) mod 1 and use the HW
    // sin/cos, whose input is in revolutions. This avoids the big-arg libm
    // slow path and is at least as accurate as the reference's f32 rounding.
    const float t0 = -trans[b * 2 + 1] * DHALF;
    const float t1 = -trans[b * 2 + 0] * DHALF;
    const float S  = fmaf(t0, px, t1 * py);      // px=i-128, py=j-128 == ki,kj
    const float rev = S * (1.0f / 256.0f);       // exact
    const float m  = rev - rintf(rev);           // exact, in [-0.5, 0.5]
    const float sn = __builtin_amdgcn_sinf(-m);  // sin(-2*pi*m)
    const float cs = __builtin_amdgcn_cosf(m);   // cos( 2*pi*m)

    const size_t ob = (size_t)b * 2 * plane + (size_t)i * DD + j;
    out[ob]         = re * cs - im * sn;
    out[ob + plane] = re * sn + im * cs;
}

extern "C" void kernel_launch(void* const* d_in, const int* in_sizes, int n_in,
                              void* d_out, int out_size, void* d_ws, size_t ws_size,
                              hipStream_t stream) {
    const float* vol   = (const float*)d_in[0];
    const float* rot   = (const float*)d_in[1];
    const float* trans = (const float*)d_in[2];
    float* out = (float*)d_out;

    const int B = in_sizes[0] / (2 * DD * DD * DD);            // 8
    const int tiles = (DD / TILE) * (DD / TILE);               // 256
    dim3 block(256);
    dim3 grid(tiles * B);                                      // 2048
    slice_extract_phase_kernel<<<grid, block, 0, stream>>>(vol, rot, trans, out);
}